// Round 3
// baseline (188.254 us; speedup 1.0000x reference)
//
#include <hip/hip_runtime.h>
#include <stdint.h>

// Problem: out[M=2048(size_out), N=8192(batch)] = W[K,M]^T @ X[N,K]^T
//   out[m,n] = sum_k W[k,m] * X[n,k]
#define M_DIM 2048
#define N_DIM 8192
#define K_DIM 2048

typedef _Float16 f16x8 __attribute__((ext_vector_type(8)));
typedef _Float16 f16x4 __attribute__((ext_vector_type(4)));
typedef float    f32x4 __attribute__((ext_vector_type(4)));

// ---------------- fused prep: cvt X (blocks 0..8191) + transpose W (8192..12287) ----------------

__global__ __launch_bounds__(256) void prep(const float* __restrict__ X,
                                            const float* __restrict__ W,
                                            _Float16* __restrict__ Xb,
                                            _Float16* __restrict__ Wt) {
    __shared__ float tile[32][33];
    int b = blockIdx.x;
    if (b < 8192) {
        size_t i = ((size_t)b * 256 + threadIdx.x) * 8;
        float4 a = *(const float4*)(X + i);
        float4 c = *(const float4*)(X + i + 4);
        f16x8 h;
        h[0] = (_Float16)a.x; h[1] = (_Float16)a.y; h[2] = (_Float16)a.z; h[3] = (_Float16)a.w;
        h[4] = (_Float16)c.x; h[5] = (_Float16)c.y; h[6] = (_Float16)c.z; h[7] = (_Float16)c.w;
        *(f16x8*)(Xb + i) = h;
    } else {
        b -= 8192;
        const int m0 = (b & 63) * 32;
        const int k0 = (b >> 6) * 32;
        const int tx = threadIdx.x & 31;
        const int ty = threadIdx.x >> 5;
#pragma unroll
        for (int i = 0; i < 32; i += 8)
            tile[ty + i][tx] = W[(size_t)(k0 + ty + i) * M_DIM + m0 + tx];
        __syncthreads();
        const int ml = threadIdx.x >> 3;
        const int kg = (threadIdx.x & 7) * 4;
        f16x4 v;
#pragma unroll
        for (int j = 0; j < 4; ++j) v[j] = (_Float16)tile[kg + j][ml];
        *(f16x4*)(Wt + (size_t)(m0 + ml) * K_DIM + k0 + kg) = v;
    }
}

// ---------------- 256x256 f16 GEMM: BK=64, 2-slot dbuf, k-half phases, B reg-cached ----------------
//
// LDS slot (64KB x2): A khalf h at SB + h*16K (256 rows x 64B), B at SB+32K + h*16K.
// Swizzle: LDS 16B-slot s of row r holds global chunk s ^ ((r>>1)&3); reads land
// 2 lanes/bank (free, m136). Staging: linear dest, inverse-swizzled source
// cg = (tid&3) ^ ((tid>>3)&3)  (rule #21: same involution both sides).
// Phases per tile (m201 dual-barrier discipline, 8 barriers, 2 counted vmcnt):
//   [vmcnt(4); bar]  Ph1: read bf(kh0)+af(mi0-3); stage A-kh0(T+1); bar; lgkm0; 16 MFMA; bar
//                    Ph2: read af(mi4-7), bf CACHED; stage B-kh0(T+1); bar; lgkm0; 16 MFMA
//   [vmcnt(4); bar]  Ph3: read bf(kh1)+af(mi0-3); stage A-kh1(T+1); bar; lgkm0; 16 MFMA; bar
//                    Ph4: read af(mi4-7); stage B-kh1(T+1); bar; lgkm0; 16 MFMA
// B single-read: 24 b128/wave/tile (was 32) = 192KB/block/tile on the shared LDS pipe.
// Stage queue order A0,B0,A1,B1: vmcnt(4) at Ph1 completes {A0,B0}(T) (3+ phases old);
// vmcnt(4) at Ph3 completes {A1,B1}(T). Last tile: no stage, Ph3 waits vmcnt(0).

__device__ __forceinline__ void load_to_lds16(const void* g, void* l) {
    __builtin_amdgcn_global_load_lds(
        (__attribute__((address_space(1))) void*)(uintptr_t)g,
        (__attribute__((address_space(3))) void*)l,
        16, 0, 0);
}

// stage one 256-row x 32-k half: 2 x global_load_lds (8KB each, 512 thr x 16B)
__device__ __forceinline__ void stage_half(const _Float16* s, int koff, char* d) {
    load_to_lds16(s + koff, d);
    load_to_lds16(s + (size_t)128 * K_DIM + koff, d + 8192);
}

template <int SLOT, bool LAST>
__device__ __forceinline__ void tile64(const char* lds, int pA, int pB,
                                       const _Float16* sa, const _Float16* sb,
                                       char* da, char* db, int snk,
                                       f32x4 (&acc)[8][4]) {
    constexpr int SB = SLOT * 65536;
    constexpr int NB = (SLOT ^ 1) * 65536;
    const char* sab = lds + SB;              // A read base
    const char* sbb = lds + SB + 32768;      // B read base
    f16x8 af[4], bf[4];

    // ================= k-half 0 =================
    asm volatile("s_waitcnt vmcnt(4)" ::: "memory");
    __builtin_amdgcn_s_barrier();
    // Ph1: bf(kh0) + af(mi0-3); stage A-kh0(next)
#pragma unroll
    for (int ni = 0; ni < 4; ++ni) bf[ni] = *(const f16x8*)(sbb + ni * 1024 + pB);
#pragma unroll
    for (int mi = 0; mi < 4; ++mi) af[mi] = *(const f16x8*)(sab + mi * 1024 + pA);
    if constexpr (!LAST) stage_half(sa, snk, da + NB);
    __builtin_amdgcn_s_barrier();
    asm volatile("s_waitcnt lgkmcnt(0)" ::: "memory");
    __builtin_amdgcn_sched_barrier(0);
    __builtin_amdgcn_s_setprio(1);
#pragma unroll
    for (int mi = 0; mi < 4; ++mi)
#pragma unroll
        for (int ni = 0; ni < 4; ++ni)
            acc[mi][ni] = __builtin_amdgcn_mfma_f32_16x16x32_f16(af[mi], bf[ni], acc[mi][ni], 0, 0, 0);
    __builtin_amdgcn_s_setprio(0);
    __builtin_amdgcn_s_barrier();
    // Ph2: af(mi4-7), bf cached; stage B-kh0(next)
#pragma unroll
    for (int mi = 0; mi < 4; ++mi) af[mi] = *(const f16x8*)(sab + (mi + 4) * 1024 + pA);
    if constexpr (!LAST) stage_half(sb, snk, db + NB);
    __builtin_amdgcn_s_barrier();
    asm volatile("s_waitcnt lgkmcnt(0)" ::: "memory");
    __builtin_amdgcn_sched_barrier(0);
    __builtin_amdgcn_s_setprio(1);
#pragma unroll
    for (int mi = 0; mi < 4; ++mi)
#pragma unroll
        for (int ni = 0; ni < 4; ++ni)
            acc[mi + 4][ni] = __builtin_amdgcn_mfma_f32_16x16x32_f16(af[mi], bf[ni], acc[mi + 4][ni], 0, 0, 0);
    __builtin_amdgcn_s_setprio(0);

    // ================= k-half 1 =================
    if constexpr (LAST) asm volatile("s_waitcnt vmcnt(0)" ::: "memory");
    else                asm volatile("s_waitcnt vmcnt(4)" ::: "memory");
    __builtin_amdgcn_s_barrier();
    // Ph3: bf(kh1) + af(mi0-3); stage A-kh1(next)
#pragma unroll
    for (int ni = 0; ni < 4; ++ni) bf[ni] = *(const f16x8*)(sbb + 16384 + ni * 1024 + pB);
#pragma unroll
    for (int mi = 0; mi < 4; ++mi) af[mi] = *(const f16x8*)(sab + 16384 + mi * 1024 + pA);
    if constexpr (!LAST) stage_half(sa, snk + 32, da + NB + 16384);
    __builtin_amdgcn_s_barrier();
    asm volatile("s_waitcnt lgkmcnt(0)" ::: "memory");
    __builtin_amdgcn_sched_barrier(0);
    __builtin_amdgcn_s_setprio(1);
#pragma unroll
    for (int mi = 0; mi < 4; ++mi)
#pragma unroll
        for (int ni = 0; ni < 4; ++ni)
            acc[mi][ni] = __builtin_amdgcn_mfma_f32_16x16x32_f16(af[mi], bf[ni], acc[mi][ni], 0, 0, 0);
    __builtin_amdgcn_s_setprio(0);
    __builtin_amdgcn_s_barrier();
    // Ph4: af(mi4-7), bf cached; stage B-kh1(next)
#pragma unroll
    for (int mi = 0; mi < 4; ++mi) af[mi] = *(const f16x8*)(sab + 16384 + (mi + 4) * 1024 + pA);
    if constexpr (!LAST) stage_half(sb, snk + 32, db + NB + 16384);
    __builtin_amdgcn_s_barrier();
    asm volatile("s_waitcnt lgkmcnt(0)" ::: "memory");
    __builtin_amdgcn_sched_barrier(0);
    __builtin_amdgcn_s_setprio(1);
#pragma unroll
    for (int mi = 0; mi < 4; ++mi)
#pragma unroll
        for (int ni = 0; ni < 4; ++ni)
            acc[mi + 4][ni] = __builtin_amdgcn_mfma_f32_16x16x32_f16(af[mi], bf[ni], acc[mi + 4][ni], 0, 0, 0);
    __builtin_amdgcn_s_setprio(0);
}

// A = Wt [M,K] f16 (K-contiguous), B = Xb [N,K] f16 (K-contiguous), C [M,N] fp32
__global__ __launch_bounds__(512, 2) void gemm_f16_256(const _Float16* __restrict__ A,
                                                       const _Float16* __restrict__ B,
                                                       float* __restrict__ C) {
    extern __shared__ char lds[];          // 2 x 64KB

    const int tid  = threadIdx.x;
    const int wave = tid >> 6;
    const int lane = tid & 63;
    const int lm = lane & 15, kq = lane >> 4;
    const int wm = wave >> 2, wn = wave & 3;   // 2x4 wave grid, each 128x64 of C

    // XCD swizzle: XCD x owns bm = x (1MB A panel L2-resident) x all 32 bn
    const int bid = ((blockIdx.x & 7) << 5) | (blockIdx.x >> 3);
    const int bm = bid >> 5;               // 0..7
    const int bn = bid & 31;               // 0..31

    // staging source (per-thread): row = tid>>2 (64B rows), inverse-swizzled chunk
    const int srow = tid >> 2;                       // 0..127
    const int cg   = ((tid & 3) ^ ((tid >> 3) & 3)) * 8;  // f16 elems
    const _Float16* sa = A + (size_t)(bm * 256 + srow) * K_DIM + cg;
    const _Float16* sb = B + (size_t)(bn * 256 + srow) * K_DIM + cg;
    char* da = lds + wave * 1024;           // A dest; + slot*65536 + h*16384 (+8192 issue1)
    char* db = lds + 32768 + wave * 1024;   // B dest

    // fragment read offsets: row r, global chunk kq at LDS slot kq ^ ((r>>1)&3);
    // r bits 1-2 come from lm only (16-aligned bases) -> lane-constant swizzle
    const int swz = (kq ^ ((lm >> 1) & 3)) * 16;
    const int pA  = wm * 8192 + lm * 64 + swz;   // + h*16384 + mi*1024
    const int pB  = wn * 4096 + lm * 64 + swz;   // + h*16384 + ni*1024 (B base +32768)

    f32x4 acc[8][4] = {};

    // prologue: tile 0 -> slot 0, queue order A0,B0,A1,B1
    stage_half(sa, 0,  da);
    stage_half(sb, 0,  db);
    stage_half(sa, 32, da + 16384);
    stage_half(sb, 32, db + 16384);

    // main loop: 32 K-tiles; tile kt in slot kt&1, stages kt+1 into other slot
#pragma unroll 1
    for (int t2 = 0; t2 < 15; ++t2) {
        const int kt = t2 * 2;
        tile64<0, false>(lds, pA, pB, sa, sb, da, db, (kt + 1) * 64, acc);
        tile64<1, false>(lds, pA, pB, sa, sb, da, db, (kt + 2) * 64, acc);
    }
    tile64<0, false>(lds, pA, pB, sa, sb, da, db, 31 * 64, acc);  // tile 30
    tile64<1, true >(lds, pA, pB, sa, sb, da, db, 0,       acc);  // tile 31, drains

    // epilogue: D row (m) = kq*4 + reg, col (n) = lm  (verified 16x16 layout)
    const int cm0 = bm * 256 + wm * 128 + kq * 4;
    const int cn0 = bn * 256 + wn * 64 + lm;
#pragma unroll
    for (int mi = 0; mi < 8; ++mi)
#pragma unroll
        for (int ni = 0; ni < 4; ++ni) {
            float* cp = C + (size_t)(cm0 + mi * 16) * N_DIM + cn0 + ni * 16;
#pragma unroll
            for (int r = 0; r < 4; ++r) cp[(size_t)r * N_DIM] = acc[mi][ni][r];
        }
}

// ---------------- fp32 fallback (only if ws too small) ----------------

__global__ __launch_bounds__(256) void gemm_f32_fallback(const float* __restrict__ X,
                                                         const float* __restrict__ W,
                                                         float* __restrict__ C) {
    __shared__ float As2[16][64];
    __shared__ float Bs2[16][64];
    const int tid = threadIdx.x;
    const int bm = blockIdx.x & 31;
    const int bn = blockIdx.x >> 5;
    const int tm = tid & 15, tn = tid >> 4;
    float c[4][4] = {};
    for (int k0 = 0; k0 < K_DIM; k0 += 16) {
        __syncthreads();
#pragma unroll
        for (int i = 0; i < 4; ++i) {
            int e = i * 256 + tid;
            As2[e >> 6][e & 63] = W[(size_t)(k0 + (e >> 6)) * M_DIM + bm * 64 + (e & 63)];
        }
#pragma unroll
        for (int i = 0; i < 4; ++i) {
            int e = i * 256 + tid;
            Bs2[e & 15][e >> 4] = X[(size_t)(bn * 64 + (e >> 4)) * K_DIM + k0 + (e & 15)];
        }
        __syncthreads();
#pragma unroll
        for (int kk = 0; kk < 16; ++kk)
#pragma unroll
            for (int i = 0; i < 4; ++i)
#pragma unroll
                for (int j = 0; j < 4; ++j)
                    c[i][j] += As2[kk][tm * 4 + i] * Bs2[kk][tn * 4 + j];
    }
#pragma unroll
    for (int i = 0; i < 4; ++i)
#pragma unroll
        for (int j = 0; j < 4; ++j)
            C[(size_t)(bm * 64 + tm * 4 + i) * N_DIM + bn * 64 + tn * 4 + j] = c[i][j];
}

// ---------------- launch ----------------

extern "C" void kernel_launch(void* const* d_in, const int* in_sizes, int n_in,
                              void* d_out, int out_size, void* d_ws, size_t ws_size,
                              hipStream_t stream) {
    const float* X = (const float*)d_in[0];  // [8192, 2048]
    const float* W = (const float*)d_in[1];  // [2048, 2048]
    // d_in[2] = bias: intentionally unused (reference discards it)
    float* C = (float*)d_out;                // [2048, 8192]

    const size_t xb_bytes = (size_t)N_DIM * K_DIM * sizeof(_Float16);  // 32 MB
    const size_t wt_bytes = (size_t)M_DIM * K_DIM * sizeof(_Float16);  //  8 MB

    if (ws_size >= xb_bytes + wt_bytes) {
        static bool attr_set = false;
        if (!attr_set) {
            (void)hipFuncSetAttribute(reinterpret_cast<const void*>(gemm_f16_256),
                                      hipFuncAttributeMaxDynamicSharedMemorySize,
                                      131072);
            attr_set = true;
        }
        _Float16* Xb = (_Float16*)d_ws;
        _Float16* Wt = (_Float16*)((char*)d_ws + xb_bytes);
        prep<<<8192 + 4096, 256, 0, stream>>>(X, W, Xb, Wt);
        gemm_f16_256<<<(M_DIM / 256) * (N_DIM / 256), 512, 131072, stream>>>(Wt, Xb, C);
    } else {
        gemm_f32_fallback<<<(M_DIM / 64) * (N_DIM / 64), 256, 0, stream>>>(X, W, C);
    }
}